// Round 13
// baseline (142.260 us; speedup 1.0000x reference)
//
#include <hip/hip_runtime.h>
#include <cmath>

#define NUM_CLS 58

typedef _Float16 v8h __attribute__((ext_vector_type(8)));
typedef float v4f __attribute__((ext_vector_type(4)));
typedef int v4i __attribute__((ext_vector_type(4)));
union HU { v8h h; uint4 u; };

// ---------------- prep v6: coalesced frag builder, 512-thread blocks ----------------
// blocks 0..127   : per-oc binarize of w3 (popcount path, phase 3)
// blocks 128..143 : w4 binarize (8 oc per block, 1 per wave)
// block  144      : w0 MFMA B-fragments (nt = wave)
// blocks 145..160 : w1/w2 -> +-1 i8 MFMA B-frags, LDS-staged coalesced
union PrepLDS { float s[1152]; float sw[18432]; };

__global__ __launch_bounds__(512) void prep_all(
    const float* __restrict__ w0, const float* __restrict__ w1,
    const float* __restrict__ w2, const float* __restrict__ w3,
    const float* __restrict__ w4,
    unsigned long long* __restrict__ wb3, unsigned long long* __restrict__ wb4,
    _Float16* __restrict__ bsig, _Float16* __restrict__ babs,
    uint4* __restrict__ bw1f, uint4* __restrict__ bw2f) {
    __shared__ PrepLDS uw;
    int id = blockIdx.x, tid = threadIdx.x;
    int lane = tid & 63, wv = tid >> 6;       // wv in 0..7
    if (id < 128) {
        int oc = id;
        const float* base = w3 + (size_t)oc * 1152;
        for (int i = tid; i < 1152; i += 512) uw.s[i] = base[i];   // coalesced
        __syncthreads();
        for (int k = wv; k < 9; k += 8) {    // stride-9 LDS reads: 2-way banks, free
            unsigned long long b0 = __ballot(uw.s[lane * 9 + k] >= 0.f);
            unsigned long long b1 = __ballot(uw.s[(lane + 64) * 9 + k] >= 0.f);
            if (lane == 0) { wb3[(oc * 9 + k) * 2] = b0; wb3[(oc * 9 + k) * 2 + 1] = b1; }
        }
    } else if (id < 144) {
        int oc = (id - 128) * 8 + wv;        // 128 oc over 16 blocks x 8 waves
        unsigned long long b0 = __ballot(w4[oc * 128 + lane] >= 0.f);
        unsigned long long b1 = __ballot(w4[oc * 128 + lane + 64] >= 0.f);
        if (lane == 0) { wb4[oc * 2] = b0; wb4[oc * 2 + 1] = b1; }
    } else if (id == 144) {
        int nt = wv;                         // 8 nt over 8 waves
        int n = nt * 16 + (lane & 15);
        int k0 = (lane >> 4) * 8;
#pragma unroll
        for (int j = 0; j < 8; j++) {
            int k = k0 + j;
            float v = (k < 27) ? w0[n * 27 + k] : 0.f;
            bsig[(nt * 64 + lane) * 8 + j] = (_Float16)v;
            babs[(nt * 64 + lane) * 8 + j] = (_Float16)fabsf(v);
        }
    } else {
        // i8 fragments: frag fi=(tk,nt,ln); byte j = sign(w[oc=nt*16+(ln&15)]
        //   [ic=kk*64+(ln>>4)*16+j][tap]). w idx = oc*1152 + ic*9 + tap.
        int fb = id - 145;                   // 0..15
        const float* w = (fb < 8) ? w1 : w2;
        uint4* o = (fb < 8) ? bw1f : bw2f;
        int nt = fb & 7;
        for (int i = tid; i < 18432; i += 512) uw.sw[i] = w[nt * 18432 + i];  // coalesced
        __syncthreads();
        for (int s = tid; s < 1152; s += 512) {
            int tk = s >> 6, ln = s & 63;
            int tap = tk >> 1, kk = tk & 1;
            int icb = kk * 64 + (ln >> 4) * 16;
            const float* base = uw.sw + (ln & 15) * 1152 + tap;
            unsigned dd[4];
#pragma unroll
            for (int q = 0; q < 4; ++q) {
                unsigned v = 0;
#pragma unroll
                for (int j = 0; j < 4; ++j)
                    v |= (base[(icb + q * 4 + j) * 9] >= 0.f ? 0x01u : 0xFFu) << (8 * j);
                dd[q] = v;
            }
            uint4 d; d.x = dd[0]; d.y = dd[1]; d.z = dd[2]; d.w = dd[3];
            o[(tk * 8 + nt) * 64 + ln] = d;
        }
    }
}

// LDS overlays: one union carries phase-0 staging, the phase-1 i8 expansion,
// and the phase-2 i8 expansion (each dead before the next is written).
union UEXP {
    struct {
        _Float16 xh[3172];                 // image f16; row stride 33, chan stride 1057
        alignas(16) uint4 bfrag[512];      // conv0 B sign-fragments (8 KB)
    } p0;
    unsigned char expb[225 * 128];         // phase1: +-1 i8 [pos][128B], XOR-swizzled chunks
    struct {
        alignas(16) unsigned char expb2[36 * 128];  // phase2: +-1 i8, 6x6 cells, swizzled
        unsigned short sgn2[16 * 8];                // conv2 window signs [win][nt]
    } p2;
};
union BS {
    alignas(16) unsigned long long bits1[450];  // [15*15][2]
    unsigned short sgn1[144 * 8];               // binconv1 window signs [w][nt]
};

// ---- fused_net: r7 champion with ONE change — phase-1b nt-fusion at mt=2 ----
// Fusion ladder status: 5+5 (r6, 40 acc) SPILL; 3+3 (r8, 24 acc + lambda)
// SPILL; lambda-rewrite (r9/r10) SPILL. r13 tests the LAST feasible point:
// mt-groups of 2 (16 acc regs), NO lambdas, NO arrays — fully scalarized
// macro blocks, unroll 1 on tk (single B-load landing set). Static liveness
// ~50 < 64. A-reads 324->162/wave (~28k LDS cyc/CU saved); B re-read per
// group (36->180 L2 loads, VMEM pipe). PRE-COMMITTED: WRITE_SIZE >= 3MB =>
// spill => fusion axis exhausted, r7 final.
__global__ __launch_bounds__(256, 4) void fused_net(
    const float* __restrict__ x, const float* __restrict__ w0,
    const _Float16* __restrict__ bsigG, const _Float16* __restrict__ babsG,
    const uint4* __restrict__ bw1f, const uint4* __restrict__ bw2f,
    const unsigned long long* __restrict__ wb3, const unsigned long long* __restrict__ wb4,
    const float* __restrict__ w5, float* __restrict__ out) {
    __shared__ UEXP u;
    __shared__ BS bs;
    __shared__ unsigned int lut[16];
    __shared__ unsigned long long bits3[18];
    __shared__ unsigned long long bits4[2];
    __shared__ float r_s[128];
    __shared__ float l_s[NUM_CLS];
    __shared__ float e_s[NUM_CLS];
    __shared__ unsigned int qcnt;
    __shared__ unsigned int queue[256];

    int b = blockIdx.x;
    int tid = threadIdx.x;
    int lane = tid & 63, wave = tid >> 6;
    const float* xb = x + (size_t)b * 3072;
    (void)babsG;   // |B| derived in-register from bsigG fragments

    // nibble -> 4 bytes of +-1 i8 LUT (used by both expansions)
    if (tid < 16) {
        unsigned int v = 0;
#pragma unroll
        for (int j = 0; j < 4; ++j) v |= (((tid >> j) & 1) ? 0x01u : 0xFFu) << (8 * j);
        lut[tid] = v;
    }

    // ================= phase 0: conv0 via f16 MFMA (pool-ordered im2col) =================
    {
        for (int i = tid; i < 3072; i += 256) {
            int c = i >> 10, rem = i & 1023;
            u.p0.xh[c * 1057 + (rem >> 5) * 33 + (rem & 31)] = (_Float16)xb[i];
        }
        const uint4* bs4 = (const uint4*)bsigG;
        for (int i = tid; i < 512; i += 256) u.p0.bfrag[i] = bs4[i];
        if (tid == 0) qcnt = 0;

        int k0 = (lane >> 4) * 8;
        int offj[8];
#pragma unroll
        for (int j = 0; j < 8; j++) {
            int k = k0 + j;
            int c = k / 9, r = (k % 9) / 3, q = k % 3;
            offj[j] = c * 1057 + r * 33 + q;
        }
        unsigned short* b1u16 = (unsigned short*)bs.bits1;
        __syncthreads();

        for (int mt = wave; mt < 57; mt += 4) {   // M = 225*4 = 900 -> 57 tiles
            int mg = mt * 16 + (lane & 15);
            int me = mg < 900 ? mg : 899;
            int p = me >> 2, win = me & 3;
            int py = p / 15, px = p - py * 15;
            int base = (py * 2 + (win >> 1)) * 33 + px * 2 + (win & 1);
            v8h a;
#pragma unroll
            for (int j = 0; j < 8; j++)
                a[j] = (k0 + j < 27) ? u.p0.xh[base + offj[j]] : (_Float16)0.f;
            HU ua; ua.h = a;                      // |A| for the error-bound MFMA
            ua.u.x &= 0x7FFF7FFFu; ua.u.y &= 0x7FFF7FFFu;
            ua.u.z &= 0x7FFF7FFFu; ua.u.w &= 0x7FFF7FFFu;
            int myp = mt * 4 + (lane >> 4);
#pragma unroll
            for (int nt = 0; nt < 8; nt++) {
                HU bsf; bsf.u = u.p0.bfrag[nt * 64 + lane];
                HU baf;                           // |B| in-register: f16 abs = clear sign bits
                baf.u.x = bsf.u.x & 0x7FFF7FFFu; baf.u.y = bsf.u.y & 0x7FFF7FFFu;
                baf.u.z = bsf.u.z & 0x7FFF7FFFu; baf.u.w = bsf.u.w & 0x7FFF7FFFu;
                v4f s  = __builtin_amdgcn_mfma_f32_16x16x32_f16(a,    bsf.h, (v4f){0.f,0.f,0.f,0.f}, 0, 0, 0);
                v4f sa = __builtin_amdgcn_mfma_f32_16x16x32_f16(ua.h, baf.h, (v4f){0.f,0.f,0.f,0.f}, 0, 0, 0);
                // rigorous f16-rounding bounds; sign logic as wave-mask ballots
                float bd0 = fmaf(sa[0], 1.1e-3f, 1e-5f);
                float bd1 = fmaf(sa[1], 1.1e-3f, 1e-5f);
                float bd2 = fmaf(sa[2], 1.1e-3f, 1e-5f);
                float bd3 = fmaf(sa[3], 1.1e-3f, 1e-5f);
                unsigned long long mkpos =
                    __ballot(s[0] >= bd0) | __ballot(s[1] >= bd1) |
                    __ballot(s[2] >= bd2) | __ballot(s[3] >= bd3);
                unsigned long long mkunc =
                    (__ballot(fabsf(s[0]) < bd0) | __ballot(fabsf(s[1]) < bd1) |
                     __ballot(fabsf(s[2]) < bd2) | __ballot(fabsf(s[3]) < bd3)) & ~mkpos;
                if ((lane & 15) == 0 && myp < 225)
                    b1u16[myp * 8 + nt] = (unsigned short)(mkpos >> (lane & 48));
                if (__builtin_expect(mkunc != 0ull, 0)) {
                    if (((mkunc >> lane) & 1ull) && myp < 225) {
                        unsigned int qi = atomicAdd(&qcnt, 1u);
                        if (qi < 256) queue[qi] = (unsigned)myp | ((unsigned)(nt * 16 + (lane & 15)) << 8);
                    }
                }
            }
        }
        __syncthreads();
        // ---- drain queue: exact f64 signs from GLOBAL f32 x (rare; all 4 windows) ----
        unsigned int nq = qcnt < 256u ? qcnt : 256u;
        for (unsigned int i = tid; i < nq; i += 256) {
            unsigned int e = queue[i];
            int p = e & 255; int oc = (e >> 8) & 255;
            int py = p / 15, px = p - py * 15;
            bool pos = false;
#pragma unroll
            for (int win = 0; win < 4; win++) {
                int base = (py * 2 + (win >> 1)) * 32 + px * 2 + (win & 1);
                double sd = 0.0;
#pragma unroll
                for (int k = 0; k < 27; k++) {
                    int c = k / 9, r = (k % 9) / 3, q = k % 3;
                    sd += (double)xb[base + c * 1024 + r * 32 + q] * (double)w0[oc * 27 + k];
                }
                pos |= (sd >= 0.0);
            }
            if (pos) atomicOr(&bs.bits1[p * 2 + (oc >> 6)], 1ull << (oc & 63));
        }
    }
    __syncthreads();

    // ========== phase 1a: expand bits1 -> +-1 i8 [225][128B], XOR-swizzled chunks ==========
    if (tid < 225) {
        ulonglong2 bw = ((const ulonglong2*)bs.bits1)[tid];
        unsigned char* dst = u.expb + tid * 128;
        int sw = (tid & 7) << 4;                   // row-XOR swizzle
#pragma unroll
        for (int c2 = 0; c2 < 2; ++c2) {
            unsigned long long v = c2 ? bw.y : bw.x;
#pragma unroll
            for (int c = 0; c < 4; ++c) {
                uint4 d;
                d.x = lut[(v >> (c * 16 +  0)) & 15];
                d.y = lut[(v >> (c * 16 +  4)) & 15];
                d.z = lut[(v >> (c * 16 +  8)) & 15];
                d.w = lut[(v >> (c * 16 + 12)) & 15];
                *(uint4*)(dst + (((c2 * 4 + c) * 16) ^ sw)) = d;
            }
        }
    }
    __syncthreads();

    // ========== phase 1b: binconv1 i8 MFMA — nt-FUSED, mt-groups of 2, scalarized ==========
    {
        int ntA = wave * 2, ntB = wave * 2 + 1;
        int cb = (lane >> 4) << 4;                 // 16B chunk base

#define BC1_GRP2(MT0) { \
        v4i a0A = (v4i){0,0,0,0}, a1A = (v4i){0,0,0,0}; \
        v4i a0B = (v4i){0,0,0,0}, a1B = (v4i){0,0,0,0}; \
        int wA = (MT0) * 16 + (lane & 15), wB = (MT0 + 1) * 16 + (lane & 15); \
        int yA = wA / 12, yB = wB / 12; \
        int pgA = (yA * 15 + wA - yA * 12) * 128 + cb; \
        int pgB = (yB * 15 + wB - yB * 12) * 128 + cb; \
        _Pragma("unroll 1") \
        for (int tk = 0; tk < 18; ++tk) { \
            int tap = tk >> 1, kk = tk & 1; \
            int tks = (tap + (tap / 3) * 12) * 128 + kk * 64; \
            uint4 br0 = bw1f[(tk * 8 + ntA) * 64 + lane]; \
            uint4 br1 = bw1f[(tk * 8 + ntB) * 64 + lane]; \
            v4i b0; b0.x = (int)br0.x; b0.y = (int)br0.y; b0.z = (int)br0.z; b0.w = (int)br0.w; \
            v4i b1; b1.x = (int)br1.x; b1.y = (int)br1.y; b1.z = (int)br1.z; b1.w = (int)br1.w; \
            int fA = pgA + tks, fB = pgB + tks; \
            v4i afA = *(const v4i*)(u.expb + (fA ^ ((fA >> 3) & 0x70))); \
            v4i afB = *(const v4i*)(u.expb + (fB ^ ((fB >> 3) & 0x70))); \
            a0A = __builtin_amdgcn_mfma_i32_16x16x64_i8(afA, b0, a0A, 0, 0, 0); \
            a1A = __builtin_amdgcn_mfma_i32_16x16x64_i8(afA, b1, a1A, 0, 0, 0); \
            a0B = __builtin_amdgcn_mfma_i32_16x16x64_i8(afB, b0, a0B, 0, 0, 0); \
            a1B = __builtin_amdgcn_mfma_i32_16x16x64_i8(afB, b1, a1B, 0, 0, 0); \
        } \
        _Pragma("unroll") \
        for (int r = 0; r < 4; ++r) { \
            unsigned long long mA0 = __ballot(a0A[r] >= 0); \
            unsigned long long mA1 = __ballot(a1A[r] >= 0); \
            unsigned long long mB0 = __ballot(a0B[r] >= 0); \
            unsigned long long mB1 = __ballot(a1B[r] >= 0); \
            if ((lane & 15) == 0) { \
                int rbA = ((MT0) * 16 + (lane >> 4) * 4 + r) * 8; \
                int rbB = ((MT0 + 1) * 16 + (lane >> 4) * 4 + r) * 8; \
                bs.sgn1[rbA + ntA] = (unsigned short)(mA0 >> lane); \
                bs.sgn1[rbA + ntB] = (unsigned short)(mA1 >> lane); \
                bs.sgn1[rbB + ntA] = (unsigned short)(mB0 >> lane); \
                bs.sgn1[rbB + ntB] = (unsigned short)(mB1 >> lane); \
            } \
        } \
    }
        BC1_GRP2(0)
        BC1_GRP2(2)
        BC1_GRP2(4)
        BC1_GRP2(6)
#undef BC1_GRP2
        {   // last group: single mt = 8
            v4i a0 = (v4i){0,0,0,0}, a1 = (v4i){0,0,0,0};
            int w = 8 * 16 + (lane & 15);
            int wy = w / 12;
            int pg = (wy * 15 + w - wy * 12) * 128 + cb;
#pragma unroll 1
            for (int tk = 0; tk < 18; ++tk) {
                int tap = tk >> 1, kk = tk & 1;
                int tks = (tap + (tap / 3) * 12) * 128 + kk * 64;
                uint4 br0 = bw1f[(tk * 8 + ntA) * 64 + lane];
                uint4 br1 = bw1f[(tk * 8 + ntB) * 64 + lane];
                v4i b0; b0.x = (int)br0.x; b0.y = (int)br0.y; b0.z = (int)br0.z; b0.w = (int)br0.w;
                v4i b1; b1.x = (int)br1.x; b1.y = (int)br1.y; b1.z = (int)br1.z; b1.w = (int)br1.w;
                int f = pg + tks;
                v4i af = *(const v4i*)(u.expb + (f ^ ((f >> 3) & 0x70)));
                a0 = __builtin_amdgcn_mfma_i32_16x16x64_i8(af, b0, a0, 0, 0, 0);
                a1 = __builtin_amdgcn_mfma_i32_16x16x64_i8(af, b1, a1, 0, 0, 0);
            }
#pragma unroll
            for (int r = 0; r < 4; ++r) {
                unsigned long long m0 = __ballot(a0[r] >= 0);
                unsigned long long m1 = __ballot(a1[r] >= 0);
                if ((lane & 15) == 0) {
                    int rb = (8 * 16 + (lane >> 4) * 4 + r) * 8;
                    bs.sgn1[rb + ntA] = (unsigned short)(m0 >> lane);
                    bs.sgn1[rb + ntB] = (unsigned short)(m1 >> lane);
                }
            }
        }
    }
    __syncthreads();

    // ========== phase 2a: pool(sgn1) -> +-1 i8 expb2 [36 cells][128B], swizzled ==========
    if (tid < 144) {
        int cell = tid >> 2, cg = tid & 3;        // cell 0..35, 32-channel group
        int cy = cell / 6, cx = cell - cy * 6;
        int w0i = (2 * cy) * 12 + 2 * cx;
        int g0 = cg * 2, g1 = cg * 2 + 1;
        unsigned v0 = (unsigned)bs.sgn1[w0i * 8 + g0]        | (unsigned)bs.sgn1[(w0i + 1) * 8 + g0]
                    | (unsigned)bs.sgn1[(w0i + 12) * 8 + g0] | (unsigned)bs.sgn1[(w0i + 13) * 8 + g0];
        unsigned v1 = (unsigned)bs.sgn1[w0i * 8 + g1]        | (unsigned)bs.sgn1[(w0i + 1) * 8 + g1]
                    | (unsigned)bs.sgn1[(w0i + 12) * 8 + g1] | (unsigned)bs.sgn1[(w0i + 13) * 8 + g1];
        unsigned vv = v0 | (v1 << 16);
        int sw = (cell & 7) << 4;
        unsigned char* dst = u.p2.expb2 + cell * 128;
        uint4 d0, d1;
        d0.x = lut[vv & 15];         d0.y = lut[(vv >> 4) & 15];
        d0.z = lut[(vv >> 8) & 15];  d0.w = lut[(vv >> 12) & 15];
        d1.x = lut[(vv >> 16) & 15]; d1.y = lut[(vv >> 20) & 15];
        d1.z = lut[(vv >> 24) & 15]; d1.w = lut[(vv >> 28) & 15];
        *(uint4*)(dst + ((cg * 32) ^ sw)) = d0;
        *(uint4*)(dst + ((cg * 32 + 16) ^ sw)) = d1;
    }
    __syncthreads();

    // ========== phase 2b: binconv2 via i8 MFMA — 16 windows = one m-tile ==========
    {
        int m = lane & 15;                         // conv2 window y2*4+x2
        int y2 = m >> 2, x2 = m & 3;
        int pg2 = (y2 * 6 + x2) * 128 + ((lane >> 4) << 4);
        int ntA = wave * 2, ntB = wave * 2 + 1;
        v4i acc0 = (v4i){0, 0, 0, 0}, acc1 = (v4i){0, 0, 0, 0};
#pragma unroll 2
        for (int tk = 0; tk < 18; ++tk) {
            int tap = tk >> 1, kk = tk & 1;
            int tapoff2 = (tap / 3) * 6 + (tap % 3);   // ky*6+kx
            int tks = tapoff2 * 128 + kk * 64;
            uint4 br0 = bw2f[(tk * 8 + ntA) * 64 + lane];
            uint4 br1 = bw2f[(tk * 8 + ntB) * 64 + lane];
            v4i b0; b0.x = (int)br0.x; b0.y = (int)br0.y; b0.z = (int)br0.z; b0.w = (int)br0.w;
            v4i b1; b1.x = (int)br1.x; b1.y = (int)br1.y; b1.z = (int)br1.z; b1.w = (int)br1.w;
            int full = pg2 + tks;
            int addr = full ^ ((full >> 3) & 0x70);
            v4i af = *(const v4i*)(u.p2.expb2 + addr);
            acc0 = __builtin_amdgcn_mfma_i32_16x16x64_i8(af, b0, acc0, 0, 0, 0);
            acc1 = __builtin_amdgcn_mfma_i32_16x16x64_i8(af, b1, acc1, 0, 0, 0);
        }
#pragma unroll
        for (int r = 0; r < 4; ++r) {
            unsigned long long m0 = __ballot(acc0[r] >= 0);
            unsigned long long m1 = __ballot(acc1[r] >= 0);
            if ((lane & 15) == 0) {
                u.p2.sgn2[(((lane >> 4) * 4 + r)) * 8 + ntA] = (unsigned short)(m0 >> lane);
                u.p2.sgn2[(((lane >> 4) * 4 + r)) * 8 + ntB] = (unsigned short)(m1 >> lane);
            }
        }
    }
    __syncthreads();

    // ========== phase 2c: maxpool(2,s1) over conv2 window signs -> bits3 ==========
    if (tid < 128) {
        int idx = tid >> 4, sh = tid & 15;         // oc = tid
        int half = tid >> 6;
        for (int p = 0; p < 9; ++p) {
            int py = p / 3, px = p - py * 3;
            int m00 = py * 4 + px;
            unsigned v = (unsigned)u.p2.sgn2[m00 * 8 + idx]       | (unsigned)u.p2.sgn2[(m00 + 1) * 8 + idx]
                       | (unsigned)u.p2.sgn2[(m00 + 4) * 8 + idx] | (unsigned)u.p2.sgn2[(m00 + 5) * 8 + idx];
            unsigned long long mm = __ballot(((v >> sh) & 1u) != 0u);
            if ((tid & 63) == 0) bits3[p * 2 + half] = mm;
        }
    }
    __syncthreads();

    // ================= phase 3: binconv3 + binconv4 + relu + w5 + softmax =================
    if (tid < 128) {
        int P = 0;
#pragma unroll
        for (int k = 0; k < 9; k++) {
            P += __popcll(bits3[k * 2] ^ wb3[tid * 18 + k * 2]);
            P += __popcll(bits3[k * 2 + 1] ^ wb3[tid * 18 + k * 2 + 1]);
        }
        unsigned long long m = __ballot(P <= 576);
        if ((tid & 63) == 0) bits4[tid >> 6] = m;
    }
    __syncthreads();
    if (tid < 128) {
        unsigned long long i0 = bits4[0], i1 = bits4[1];
        int v = 128 - 2 * (int)(__popcll(i0 ^ wb4[tid * 2]) + __popcll(i1 ^ wb4[tid * 2 + 1]));
        r_s[tid] = v > 0 ? (float)v : 0.f;   // relu
    }
    __syncthreads();
    if (tid < NUM_CLS) {
        float l = 0.f;
#pragma unroll 8
        for (int k = 0; k < 128; k++) l = fmaf(w5[tid * 128 + k], r_s[k], l);
        l_s[tid] = l;
    }
    __syncthreads();
    if (tid < NUM_CLS) {
        float mx = -1e30f;
        for (int k = 0; k < NUM_CLS; k++) mx = fmaxf(mx, l_s[k]);
        e_s[tid] = expf(l_s[tid] - mx);
    }
    __syncthreads();
    if (tid < NUM_CLS) {
        float sum = 0.f;
        for (int k = 0; k < NUM_CLS; k++) sum += e_s[k];
        out[(size_t)b * NUM_CLS + tid] = e_s[tid] / sum;
    }
}

extern "C" void kernel_launch(void* const* d_in, const int* in_sizes, int n_in,
                              void* d_out, int out_size, void* d_ws, size_t ws_size,
                              hipStream_t stream) {
    const float* x  = (const float*)d_in[0];
    const float* w0 = (const float*)d_in[1];
    const float* w1 = (const float*)d_in[2];
    const float* w2 = (const float*)d_in[3];
    const float* w3 = (const float*)d_in[4];
    const float* w4 = (const float*)d_in[5];
    const float* w5 = (const float*)d_in[6];
    float* out = (float*)d_out;

    int B = in_sizes[0] / 3072;   // 1024

    size_t off = 0;
    auto carve = [&](size_t bytes) {
        void* p = (char*)d_ws + off;
        off += (bytes + 255) & ~(size_t)255;
        return p;
    };
    unsigned long long* wb3 = (unsigned long long*)carve(1152 * 2 * 8);
    unsigned long long* wb4 = (unsigned long long*)carve(128 * 2 * 8);
    _Float16* bsig = (_Float16*)carve(8 * 64 * 8 * 2);   // conv0 MFMA B-frags (signed)
    _Float16* babs = (_Float16*)carve(8 * 64 * 8 * 2);   // conv0 MFMA B-frags (abs, unused by fused_net)
    uint4* bw1f = (uint4*)carve(18 * 8 * 64 * 16);       // w1 i8 frags, 147456 B
    uint4* bw2f = (uint4*)carve(18 * 8 * 64 * 16);       // w2 i8 frags, 147456 B
    (void)ws_size; (void)n_in; (void)out_size;

    prep_all<<<161, 512, 0, stream>>>(w0, w1, w2, w3, w4, wb3, wb4, bsig, babs, bw1f, bw2f);
    fused_net<<<B, 256, 0, stream>>>(x, w0, bsig, babs, bw1f, bw2f, wb3, wb4, w5, out);
}

// Round 14
// 132.055 us; speedup vs baseline: 1.0773x; 1.0773x over previous
//
#include <hip/hip_runtime.h>
#include <cmath>

#define NUM_CLS 58

typedef _Float16 v8h __attribute__((ext_vector_type(8)));
typedef float v4f __attribute__((ext_vector_type(4)));
typedef int v4i __attribute__((ext_vector_type(4)));
union HU { v8h h; uint4 u; };

// ---------------- prep v5 (r7's — measured best bench-gap) ----------------
// blocks 0..127   : per-oc binarize of w3 (popcount path, phase 3)
// blocks 128..159 : w4 binarize (1 oc per wave)
// blocks 160..161 : w0 MFMA B-fragments, signed + abs (4 nt per block)
// blocks 162..197 : w1 -> +-1 i8 MFMA B-frags [tk=18][nt=8][lane=64][16B]
// blocks 198..233 : w2 -> same fragment format (binconv2 MFMA)
__global__ __launch_bounds__(256) void prep_all(
    const float* __restrict__ w0, const float* __restrict__ w1,
    const float* __restrict__ w2, const float* __restrict__ w3,
    const float* __restrict__ w4,
    unsigned long long* __restrict__ wb3, unsigned long long* __restrict__ wb4,
    _Float16* __restrict__ bsig, _Float16* __restrict__ babs,
    uint4* __restrict__ bw1f, uint4* __restrict__ bw2f) {
    int id = blockIdx.x, tid = threadIdx.x;
    int lane = tid & 63, wv = tid >> 6;
    if (id < 128) {
        int oc = id;
        __shared__ float s[1152];
        const float* base = w3 + (size_t)oc * 1152;
        for (int i = tid; i < 1152; i += 256) s[i] = base[i];   // coalesced
        __syncthreads();
        for (int k = wv; k < 9; k += 4) {    // stride-9 LDS reads: 2-way banks, free
            unsigned long long b0 = __ballot(s[lane * 9 + k] >= 0.f);
            unsigned long long b1 = __ballot(s[(lane + 64) * 9 + k] >= 0.f);
            if (lane == 0) { wb3[(oc * 9 + k) * 2] = b0; wb3[(oc * 9 + k) * 2 + 1] = b1; }
        }
    } else if (id < 160) {
        int oc = (id - 128) * 4 + wv;        // 128 oc over 32 blocks x 4 waves
        unsigned long long b0 = __ballot(w4[oc * 128 + lane] >= 0.f);
        unsigned long long b1 = __ballot(w4[oc * 128 + lane + 64] >= 0.f);
        if (lane == 0) { wb4[oc * 2] = b0; wb4[oc * 2 + 1] = b1; }
    } else if (id < 162) {
        int nt = (id - 160) * 4 + wv;        // 8 nt over 2 blocks x 4 waves
        int n = nt * 16 + (lane & 15);
        int k0 = (lane >> 4) * 8;
#pragma unroll
        for (int j = 0; j < 8; j++) {
            int k = k0 + j;
            float v = (k < 27) ? w0[n * 27 + k] : 0.f;
            bsig[(nt * 64 + lane) * 8 + j] = (_Float16)v;
            babs[(nt * 64 + lane) * 8 + j] = (_Float16)fabsf(v);
        }
    } else {
        // i8 fragments for w1/w2: frag fi=(tk,nt,ln); byte j = sign(w[oc=nt*16+(ln&15)]
        //   [ic=kk*64+(ln>>4)*16+j][tap]) as +1/-1 i8. w idx = oc*1152 + ic*9 + tap.
        bool isw1 = id < 198;
        const float* w = isw1 ? w1 : w2;
        uint4* o = isw1 ? bw1f : bw2f;
        int fi = (isw1 ? id - 162 : id - 198) * 256 + tid;   // 0..9215
        int tk = fi >> 9;                    // 0..17 (tap*2+kk)
        int rem = fi & 511;
        int nt = rem >> 6, ln = rem & 63;
        int oc = nt * 16 + (ln & 15);
        int tap = tk >> 1, kk = tk & 1;
        int icb = kk * 64 + (ln >> 4) * 16;
        const float* wp = w + (size_t)oc * 1152 + tap;
        unsigned int dd[4];
#pragma unroll
        for (int q = 0; q < 4; ++q) {
            unsigned int v = 0;
#pragma unroll
            for (int j = 0; j < 4; ++j)
                v |= (wp[(icb + q * 4 + j) * 9] >= 0.f ? 0x01u : 0xFFu) << (8 * j);
            dd[q] = v;
        }
        uint4 d; d.x = dd[0]; d.y = dd[1]; d.z = dd[2]; d.w = dd[3];
        o[fi] = d;
    }
}

// LDS overlays: one union carries phase-0 staging, the phase-1 i8 expansion,
// and the phase-2 i8 expansion (each dead before the next is written).
union UEXP {
    struct {
        _Float16 xh[3172];                 // image f16; row stride 33, chan stride 1057
        alignas(16) uint4 bfrag[512];      // conv0 B sign-fragments (8 KB)
    } p0;
    unsigned char expb[225 * 128];         // phase1: +-1 i8 [pos][128B], XOR-swizzled chunks
    struct {
        alignas(16) unsigned char expb2[36 * 128];  // phase2: +-1 i8, 6x6 cells, swizzled
        unsigned short sgn2[16 * 8];                // conv2 window signs [win][nt]
    } p2;
};
union BS {
    alignas(16) unsigned long long bits1[450];  // [15*15][2]
    unsigned short sgn1[144 * 8];               // binconv1 window signs [w][nt]
};

// ---- fused_net = r7 champion (70.2us measured) + T5 setprio on MFMA phases ----
// LEDGER (13 rounds): occupancy >4 waves/SIMD spills (r1/r2: 64-VGPR wall,
// arch/acc 50/50 split); phase-1b conflicts are OFF the critical path (r11:
// swizzle class irrelevant; r13: halving them REGRESSED via unroll-1 latency);
// A-read-halving fails 4 ways at the wall (r6/r8/r9-r10/r13); prep & launch
// gap (~62us) is harness-fixed (r12). Regime: dependency-latency-bound at
// register-wall-capped TLP. T5 rationale: 4 blocks/CU desync after phase 0
// (data-dependent drain-queue length) -> mixed-phase waves per SIMD ->
// priority keeps matrix pipe fed (null if lockstep, per m190/m191).
__global__ __launch_bounds__(256, 4) void fused_net(
    const float* __restrict__ x, const float* __restrict__ w0,
    const _Float16* __restrict__ bsigG, const _Float16* __restrict__ babsG,
    const uint4* __restrict__ bw1f, const uint4* __restrict__ bw2f,
    const unsigned long long* __restrict__ wb3, const unsigned long long* __restrict__ wb4,
    const float* __restrict__ w5, float* __restrict__ out) {
    __shared__ UEXP u;
    __shared__ BS bs;
    __shared__ unsigned int lut[16];
    __shared__ unsigned long long bits3[18];
    __shared__ unsigned long long bits4[2];
    __shared__ float r_s[128];
    __shared__ float l_s[NUM_CLS];
    __shared__ float e_s[NUM_CLS];
    __shared__ unsigned int qcnt;
    __shared__ unsigned int queue[256];

    int b = blockIdx.x;
    int tid = threadIdx.x;
    int lane = tid & 63, wave = tid >> 6;
    const float* xb = x + (size_t)b * 3072;
    (void)babsG;   // |B| derived in-register from bsigG fragments

    // nibble -> 4 bytes of +-1 i8 LUT (used by both expansions)
    if (tid < 16) {
        unsigned int v = 0;
#pragma unroll
        for (int j = 0; j < 4; ++j) v |= (((tid >> j) & 1) ? 0x01u : 0xFFu) << (8 * j);
        lut[tid] = v;
    }

    // ================= phase 0: conv0 via f16 MFMA (pool-ordered im2col) =================
    {
        for (int i = tid; i < 3072; i += 256) {
            int c = i >> 10, rem = i & 1023;
            u.p0.xh[c * 1057 + (rem >> 5) * 33 + (rem & 31)] = (_Float16)xb[i];
        }
        const uint4* bs4 = (const uint4*)bsigG;
        for (int i = tid; i < 512; i += 256) u.p0.bfrag[i] = bs4[i];
        if (tid == 0) qcnt = 0;

        int k0 = (lane >> 4) * 8;
        int offj[8];
#pragma unroll
        for (int j = 0; j < 8; j++) {
            int k = k0 + j;
            int c = k / 9, r = (k % 9) / 3, q = k % 3;
            offj[j] = c * 1057 + r * 33 + q;
        }
        unsigned short* b1u16 = (unsigned short*)bs.bits1;
        __syncthreads();

        for (int mt = wave; mt < 57; mt += 4) {   // M = 225*4 = 900 -> 57 tiles
            int mg = mt * 16 + (lane & 15);
            int me = mg < 900 ? mg : 899;
            int p = me >> 2, win = me & 3;
            int py = p / 15, px = p - py * 15;
            int base = (py * 2 + (win >> 1)) * 33 + px * 2 + (win & 1);
            v8h a;
#pragma unroll
            for (int j = 0; j < 8; j++)
                a[j] = (k0 + j < 27) ? u.p0.xh[base + offj[j]] : (_Float16)0.f;
            HU ua; ua.h = a;                      // |A| for the error-bound MFMA
            ua.u.x &= 0x7FFF7FFFu; ua.u.y &= 0x7FFF7FFFu;
            ua.u.z &= 0x7FFF7FFFu; ua.u.w &= 0x7FFF7FFFu;
            int myp = mt * 4 + (lane >> 4);
#pragma unroll
            for (int nt = 0; nt < 8; nt++) {
                HU bsf; bsf.u = u.p0.bfrag[nt * 64 + lane];
                HU baf;                           // |B| in-register: f16 abs = clear sign bits
                baf.u.x = bsf.u.x & 0x7FFF7FFFu; baf.u.y = bsf.u.y & 0x7FFF7FFFu;
                baf.u.z = bsf.u.z & 0x7FFF7FFFu; baf.u.w = bsf.u.w & 0x7FFF7FFFu;
                v4f s  = __builtin_amdgcn_mfma_f32_16x16x32_f16(a,    bsf.h, (v4f){0.f,0.f,0.f,0.f}, 0, 0, 0);
                v4f sa = __builtin_amdgcn_mfma_f32_16x16x32_f16(ua.h, baf.h, (v4f){0.f,0.f,0.f,0.f}, 0, 0, 0);
                // rigorous f16-rounding bounds; sign logic as wave-mask ballots
                float bd0 = fmaf(sa[0], 1.1e-3f, 1e-5f);
                float bd1 = fmaf(sa[1], 1.1e-3f, 1e-5f);
                float bd2 = fmaf(sa[2], 1.1e-3f, 1e-5f);
                float bd3 = fmaf(sa[3], 1.1e-3f, 1e-5f);
                unsigned long long mkpos =
                    __ballot(s[0] >= bd0) | __ballot(s[1] >= bd1) |
                    __ballot(s[2] >= bd2) | __ballot(s[3] >= bd3);
                unsigned long long mkunc =
                    (__ballot(fabsf(s[0]) < bd0) | __ballot(fabsf(s[1]) < bd1) |
                     __ballot(fabsf(s[2]) < bd2) | __ballot(fabsf(s[3]) < bd3)) & ~mkpos;
                if ((lane & 15) == 0 && myp < 225)
                    b1u16[myp * 8 + nt] = (unsigned short)(mkpos >> (lane & 48));
                if (__builtin_expect(mkunc != 0ull, 0)) {
                    if (((mkunc >> lane) & 1ull) && myp < 225) {
                        unsigned int qi = atomicAdd(&qcnt, 1u);
                        if (qi < 256) queue[qi] = (unsigned)myp | ((unsigned)(nt * 16 + (lane & 15)) << 8);
                    }
                }
            }
        }
        __syncthreads();
        // ---- drain queue: exact f64 signs from GLOBAL f32 x (rare; all 4 windows) ----
        unsigned int nq = qcnt < 256u ? qcnt : 256u;
        for (unsigned int i = tid; i < nq; i += 256) {
            unsigned int e = queue[i];
            int p = e & 255; int oc = (e >> 8) & 255;
            int py = p / 15, px = p - py * 15;
            bool pos = false;
#pragma unroll
            for (int win = 0; win < 4; win++) {
                int base = (py * 2 + (win >> 1)) * 32 + px * 2 + (win & 1);
                double sd = 0.0;
#pragma unroll
                for (int k = 0; k < 27; k++) {
                    int c = k / 9, r = (k % 9) / 3, q = k % 3;
                    sd += (double)xb[base + c * 1024 + r * 32 + q] * (double)w0[oc * 27 + k];
                }
                pos |= (sd >= 0.0);
            }
            if (pos) atomicOr(&bs.bits1[p * 2 + (oc >> 6)], 1ull << (oc & 63));
        }
    }
    __syncthreads();

    // ========== phase 1a: expand bits1 -> +-1 i8 [225][128B], XOR-swizzled chunks ==========
    if (tid < 225) {
        ulonglong2 bw = ((const ulonglong2*)bs.bits1)[tid];
        unsigned char* dst = u.expb + tid * 128;
        int sw = (tid & 7) << 4;                   // row-XOR swizzle
#pragma unroll
        for (int c2 = 0; c2 < 2; ++c2) {
            unsigned long long v = c2 ? bw.y : bw.x;
#pragma unroll
            for (int c = 0; c < 4; ++c) {
                uint4 d;
                d.x = lut[(v >> (c * 16 +  0)) & 15];
                d.y = lut[(v >> (c * 16 +  4)) & 15];
                d.z = lut[(v >> (c * 16 +  8)) & 15];
                d.w = lut[(v >> (c * 16 + 12)) & 15];
                *(uint4*)(dst + (((c2 * 4 + c) * 16) ^ sw)) = d;
            }
        }
    }
    __syncthreads();

    // ========== phase 1b: binconv1 via i8 MFMA (r7 structure) + T5 setprio ==========
    {
        int pg_[9];                                // pos*128 + (lane>>4)*16
#pragma unroll
        for (int mt = 0; mt < 9; ++mt) {
            int w = mt * 16 + (lane & 15);         // window row 0..143
            int wy = w / 12, wx = w - wy * 12;
            pg_[mt] = (wy * 15 + wx) * 128 + ((lane >> 4) << 4);
        }

        __builtin_amdgcn_s_setprio(1);             // favor MFMA waves vs other blocks' VALU phases
        for (int pass = 0; pass < 2; ++pass) {
            int nt = wave * 2 + pass;
            v4i acc[9];
#pragma unroll
            for (int mt = 0; mt < 9; ++mt) acc[mt] = (v4i){0, 0, 0, 0};
#pragma unroll 2
            for (int tk = 0; tk < 18; ++tk) {      // tap*2+kk
                int tap = tk >> 1, kk = tk & 1;
                int tapoff = tap + (tap / 3) * 12; // ky*15+kx
                int tks = tapoff * 128 + kk * 64;
                uint4 bfr = bw1f[(tk * 8 + nt) * 64 + lane];
                v4i bf; bf.x = (int)bfr.x; bf.y = (int)bfr.y; bf.z = (int)bfr.z; bf.w = (int)bfr.w;
#pragma unroll
                for (int mt = 0; mt < 9; ++mt) {
                    // row = pos+tapoff; chunk<128 never carries into bit7, so
                    // full ^ ((full>>3)&0x70) == row*128 + (chunk16 ^ ((row&7)<<4))
                    int full = pg_[mt] + tks;
                    int addr = full ^ ((full >> 3) & 0x70);
                    v4i af = *(const v4i*)(u.expb + addr);
                    acc[mt] = __builtin_amdgcn_mfma_i32_16x16x64_i8(af, bf, acc[mt], 0, 0, 0);
                }
            }
            // signs -> sgn1[w][nt] as u16 oc-slices (same ballot idiom as phase 0)
#pragma unroll
            for (int mt = 0; mt < 9; ++mt) {
#pragma unroll
                for (int r = 0; r < 4; ++r) {
                    unsigned long long mm = __ballot(acc[mt][r] >= 0);
                    if ((lane & 15) == 0)
                        bs.sgn1[(mt * 16 + (lane >> 4) * 4 + r) * 8 + nt] =
                            (unsigned short)(mm >> lane);
                }
            }
        }
        __builtin_amdgcn_s_setprio(0);
    }
    __syncthreads();

    // ========== phase 2a: pool(sgn1) -> +-1 i8 expb2 [36 cells][128B], swizzled ==========
    if (tid < 144) {
        int cell = tid >> 2, cg = tid & 3;        // cell 0..35, 32-channel group
        int cy = cell / 6, cx = cell - cy * 6;
        int w0i = (2 * cy) * 12 + 2 * cx;
        int g0 = cg * 2, g1 = cg * 2 + 1;
        unsigned v0 = (unsigned)bs.sgn1[w0i * 8 + g0]        | (unsigned)bs.sgn1[(w0i + 1) * 8 + g0]
                    | (unsigned)bs.sgn1[(w0i + 12) * 8 + g0] | (unsigned)bs.sgn1[(w0i + 13) * 8 + g0];
        unsigned v1 = (unsigned)bs.sgn1[w0i * 8 + g1]        | (unsigned)bs.sgn1[(w0i + 1) * 8 + g1]
                    | (unsigned)bs.sgn1[(w0i + 12) * 8 + g1] | (unsigned)bs.sgn1[(w0i + 13) * 8 + g1];
        unsigned vv = v0 | (v1 << 16);
        int sw = (cell & 7) << 4;
        unsigned char* dst = u.p2.expb2 + cell * 128;
        uint4 d0, d1;
        d0.x = lut[vv & 15];         d0.y = lut[(vv >> 4) & 15];
        d0.z = lut[(vv >> 8) & 15];  d0.w = lut[(vv >> 12) & 15];
        d1.x = lut[(vv >> 16) & 15]; d1.y = lut[(vv >> 20) & 15];
        d1.z = lut[(vv >> 24) & 15]; d1.w = lut[(vv >> 28) & 15];
        *(uint4*)(dst + ((cg * 32) ^ sw)) = d0;
        *(uint4*)(dst + ((cg * 32 + 16) ^ sw)) = d1;
    }
    __syncthreads();

    // ========== phase 2b: binconv2 via i8 MFMA — 16 windows = one m-tile, setprio ==========
    {
        int m = lane & 15;                         // conv2 window y2*4+x2
        int y2 = m >> 2, x2 = m & 3;
        int pg2 = (y2 * 6 + x2) * 128 + ((lane >> 4) << 4);
        int ntA = wave * 2, ntB = wave * 2 + 1;
        v4i acc0 = (v4i){0, 0, 0, 0}, acc1 = (v4i){0, 0, 0, 0};
        __builtin_amdgcn_s_setprio(1);
#pragma unroll 2
        for (int tk = 0; tk < 18; ++tk) {
            int tap = tk >> 1, kk = tk & 1;
            int tapoff2 = (tap / 3) * 6 + (tap % 3);   // ky*6+kx
            int tks = tapoff2 * 128 + kk * 64;
            uint4 br0 = bw2f[(tk * 8 + ntA) * 64 + lane];
            uint4 br1 = bw2f[(tk * 8 + ntB) * 64 + lane];
            v4i b0; b0.x = (int)br0.x; b0.y = (int)br0.y; b0.z = (int)br0.z; b0.w = (int)br0.w;
            v4i b1; b1.x = (int)br1.x; b1.y = (int)br1.y; b1.z = (int)br1.z; b1.w = (int)br1.w;
            int full = pg2 + tks;
            int addr = full ^ ((full >> 3) & 0x70);
            v4i af = *(const v4i*)(u.p2.expb2 + addr);
            acc0 = __builtin_amdgcn_mfma_i32_16x16x64_i8(af, b0, acc0, 0, 0, 0);
            acc1 = __builtin_amdgcn_mfma_i32_16x16x64_i8(af, b1, acc1, 0, 0, 0);
        }
        __builtin_amdgcn_s_setprio(0);
#pragma unroll
        for (int r = 0; r < 4; ++r) {
            unsigned long long m0 = __ballot(acc0[r] >= 0);
            unsigned long long m1 = __ballot(acc1[r] >= 0);
            if ((lane & 15) == 0) {
                u.p2.sgn2[(((lane >> 4) * 4 + r)) * 8 + ntA] = (unsigned short)(m0 >> lane);
                u.p2.sgn2[(((lane >> 4) * 4 + r)) * 8 + ntB] = (unsigned short)(m1 >> lane);
            }
        }
    }
    __syncthreads();

    // ========== phase 2c: maxpool(2,s1) over conv2 window signs -> bits3 ==========
    if (tid < 128) {
        int idx = tid >> 4, sh = tid & 15;         // oc = tid
        int half = tid >> 6;
        for (int p = 0; p < 9; ++p) {
            int py = p / 3, px = p - py * 3;
            int m00 = py * 4 + px;
            unsigned v = (unsigned)u.p2.sgn2[m00 * 8 + idx]       | (unsigned)u.p2.sgn2[(m00 + 1) * 8 + idx]
                       | (unsigned)u.p2.sgn2[(m00 + 4) * 8 + idx] | (unsigned)u.p2.sgn2[(m00 + 5) * 8 + idx];
            unsigned long long mm = __ballot(((v >> sh) & 1u) != 0u);
            if ((tid & 63) == 0) bits3[p * 2 + half] = mm;
        }
    }
    __syncthreads();

    // ================= phase 3: binconv3 + binconv4 + relu + w5 + softmax =================
    if (tid < 128) {
        int P = 0;
#pragma unroll
        for (int k = 0; k < 9; k++) {
            P += __popcll(bits3[k * 2] ^ wb3[tid * 18 + k * 2]);
            P += __popcll(bits3[k * 2 + 1] ^ wb3[tid * 18 + k * 2 + 1]);
        }
        unsigned long long m = __ballot(P <= 576);
        if ((tid & 63) == 0) bits4[tid >> 6] = m;
    }
    __syncthreads();
    if (tid < 128) {
        unsigned long long i0 = bits4[0], i1 = bits4[1];
        int v = 128 - 2 * (int)(__popcll(i0 ^ wb4[tid * 2]) + __popcll(i1 ^ wb4[tid * 2 + 1]));
        r_s[tid] = v > 0 ? (float)v : 0.f;   // relu
    }
    __syncthreads();
    if (tid < NUM_CLS) {
        float l = 0.f;
#pragma unroll 8
        for (int k = 0; k < 128; k++) l = fmaf(w5[tid * 128 + k], r_s[k], l);
        l_s[tid] = l;
    }
    __syncthreads();
    if (tid < NUM_CLS) {
        float mx = -1e30f;
        for (int k = 0; k < NUM_CLS; k++) mx = fmaxf(mx, l_s[k]);
        e_s[tid] = expf(l_s[tid] - mx);
    }
    __syncthreads();
    if (tid < NUM_CLS) {
        float sum = 0.f;
        for (int k = 0; k < NUM_CLS; k++) sum += e_s[k];
        out[(size_t)b * NUM_CLS + tid] = e_s[tid] / sum;
    }
}

extern "C" void kernel_launch(void* const* d_in, const int* in_sizes, int n_in,
                              void* d_out, int out_size, void* d_ws, size_t ws_size,
                              hipStream_t stream) {
    const float* x  = (const float*)d_in[0];
    const float* w0 = (const float*)d_in[1];
    const float* w1 = (const float*)d_in[2];
    const float* w2 = (const float*)d_in[3];
    const float* w3 = (const float*)d_in[4];
    const float* w4 = (const float*)d_in[5];
    const float* w5 = (const float*)d_in[6];
    float* out = (float*)d_out;

    int B = in_sizes[0] / 3072;   // 1024

    size_t off = 0;
    auto carve = [&](size_t bytes) {
        void* p = (char*)d_ws + off;
        off += (bytes + 255) & ~(size_t)255;
        return p;
    };
    unsigned long long* wb3 = (unsigned long long*)carve(1152 * 2 * 8);
    unsigned long long* wb4 = (unsigned long long*)carve(128 * 2 * 8);
    _Float16* bsig = (_Float16*)carve(8 * 64 * 8 * 2);   // conv0 MFMA B-frags (signed)
    _Float16* babs = (_Float16*)carve(8 * 64 * 8 * 2);   // conv0 MFMA B-frags (abs, unused by fused_net)
    uint4* bw1f = (uint4*)carve(18 * 8 * 64 * 16);       // w1 i8 frags, 147456 B
    uint4* bw2f = (uint4*)carve(18 * 8 * 64 * 16);       // w2 i8 frags, 147456 B
    (void)ws_size; (void)n_in; (void)out_size;

    prep_all<<<234, 256, 0, stream>>>(w0, w1, w2, w3, w4, wb3, wb4, bsig, babs, bw1f, bw2f);
    fused_net<<<B, 256, 0, stream>>>(x, w0, bsig, babs, bw1f, bw2f, wb3, wb4, w5, out);
}